// Round 7
// baseline (157.500 us; speedup 1.0000x reference)
//
#include <hip/hip_runtime.h>
#include <math.h>
#include <stdint.h>

#define BB 16
#define DD 96
#define TT 512
#define HH 1024
#define NROW (BB*DD)   // 1536

typedef __attribute__((ext_vector_type(4))) float floatx4;
typedef __attribute__((ext_vector_type(8))) short short8;

// ---------------- ws layout (bytes) ----------------
#define WSOFF_X     0                               // attn out fp32, 3MB
#define WSOFF_XROW  (3*1024*1024)                   // xn row-major bf16, 1.5MB
#define WSOFF_XFRAG (WSOFF_XROW + NROW*TT*2)        // xn gemm1-A-frag bf16, 1.5MB
#define WSOFF_W1BF  (WSOFF_XFRAG + NROW*TT*2)       // 1MB
#define WSOFF_W2BF  (WSOFF_W1BF + TT*HH*2)          // 1MB
#define WSOFF_A     (WSOFF_W2BF + HH*TT*2)          // 576KB
#define WSOFF_P1    (WSOFF_A + BB*DD*DD*4)          // 96*128 fp32 partial sums
#define WSOFF_P2    (WSOFF_P1 + DD*128*4)           // 96*128 fp32 partial sumsq

__device__ __forceinline__ uint16_t f2bf(float v) {
    uint32_t u = __float_as_uint(v);
    uint32_t r = 0x7fffu + ((u >> 16) & 1u);
    return (uint16_t)((u + r) >> 16);
}
__device__ __forceinline__ float bf2f(uint16_t v) {
    return __uint_as_float(((uint32_t)v) << 16);
}

#define KT1 (TT/32)    // 16 k-tiles, gemm1 A
__device__ __forceinline__ size_t afrag1_slot(int row, int k) {
    return ((size_t)((row >> 4)*KT1 + (k >> 5))*64 + ((k >> 3) & 3)*16 + (row & 15));
}

// K1: per batch b: row sums (4 waves x 24 rows) then softmax -> A[b]
__global__ __launch_bounds__(256) void k_prep(const float* __restrict__ r,
                                              float* __restrict__ A) {
    __shared__ float sl[DD];
    int b = blockIdx.x;
    int tid = threadIdx.x;
    int w = tid >> 6, lane = tid & 63;
    for (int rr = 0; rr < 24; ++rr) {
        int i = w*24 + rr;
        const float* p = r + ((size_t)b*DD + i)*TT;
        float acc = 0.f;
        #pragma unroll
        for (int s = 0; s < TT/64; ++s) acc += p[lane + s*64];
        #pragma unroll
        for (int o = 32; o > 0; o >>= 1) acc += __shfl_down(acc, o, 64);
        if (lane == 0) sl[i] = acc;
    }
    __syncthreads();
    int i = tid;
    if (i < DD) {
        const float c = 1.0f / (512.0f * 22.627416997969522f);  // T^-1.5
        float si = sl[i] * c;
        float m = -1e30f;
        for (int j = 0; j < DD; ++j) m = fmaxf(m, si * sl[j]);
        float sum = 0.f;
        for (int j = 0; j < DD; ++j) sum += expf(si * sl[j] - m);
        float inv = 1.0f / sum;
        float* Ao = A + ((size_t)b*DD + i)*DD;
        for (int j = 0; j < DD; ++j) Ao[j] = expf(si * sl[j] - m) * inv;
    }
}

// K2: blocks [0,512): wswiz (wave handles one 64-lane chunk); [512,1024): attn + BN partials.
__global__ __launch_bounds__(256) void k_attw(const float* __restrict__ r,
                                              const float* __restrict__ A,
                                              const float* __restrict__ W1,
                                              const float* __restrict__ W2,
                                              float* __restrict__ x,
                                              uint16_t* __restrict__ w1bf,
                                              uint16_t* __restrict__ w2bf,
                                              float* __restrict__ P1,
                                              float* __restrict__ P2) {
    int bx = blockIdx.x;
    int tid = threadIdx.x;
    int w = tid >> 6, lane = tid & 63;
    if (bx < 512) {
        // ---- weight swizzle: chunk = bx*4 + w, 2048 chunks total ----
        int blk = bx*4 + w;
        int q = lane >> 4, l15 = lane & 15;
        const float* W; uint16_t* out; int KT, N, b;
        if (blk < 1024) { W = W1; out = w1bf; KT = 16; N = 1024; b = blk; }
        else            { W = W2; out = w2bf; KT = 32; N = 512;  b = blk - 1024; }
        int tile_n = b / KT, tile_k = b % KT;
        const float* src = W + (size_t)(tile_k*32 + q*8)*N + tile_n*16 + l15;
        uint16_t tmp[8];
        #pragma unroll
        for (int j = 0; j < 8; ++j) tmp[j] = f2bf(src[(size_t)j*N]);
        uint16_t* dst = out + ((size_t)b*64 + lane)*8;
        *reinterpret_cast<ushort4*>(dst)     = *reinterpret_cast<ushort4*>(&tmp[0]);
        *reinterpret_cast<ushort4*>(dst + 4) = *reinterpret_cast<ushort4*>(&tmp[4]);
        return;
    }
    // ---- attention: x = A @ r + r, plus per-(b,chunk) channel partials ----
    __shared__ float rlds[DD*64];
    int idx = bx - 512;
    int b = idx & 15, chunk = (idx >> 4) & 7, ig = idx >> 7;
    int t0 = chunk * 64;
    const float4* rb4 = reinterpret_cast<const float4*>(r + (size_t)b*DD*TT);
    float4* rl4 = reinterpret_cast<float4*>(rlds);
    #pragma unroll
    for (int s = 0; s < 6; ++s) {
        int ii = tid + s*256;
        rl4[ii] = rb4[(size_t)(ii >> 4)*(TT/4) + (t0 >> 2) + (ii & 15)];
    }
    __syncthreads();
    int wu = __builtin_amdgcn_readfirstlane(w);
    int i0 = ig*24 + wu*6;
    const float* Ab = A + ((size_t)b*DD + i0)*DD;
    float acc[6];
    #pragma unroll
    for (int rr = 0; rr < 6; ++rr) acc[rr] = rlds[(i0+rr)*64 + lane];
    #pragma unroll 4
    for (int j4 = 0; j4 < DD/4; ++j4) {
        float4 a[6];
        #pragma unroll
        for (int rr = 0; rr < 6; ++rr)
            a[rr] = *reinterpret_cast<const float4*>(Ab + rr*DD + j4*4);
        float rv[4];
        #pragma unroll
        for (int u = 0; u < 4; ++u) rv[u] = rlds[(j4*4+u)*64 + lane];
        #pragma unroll
        for (int rr = 0; rr < 6; ++rr) {
            acc[rr] = fmaf(a[rr].x, rv[0], acc[rr]);
            acc[rr] = fmaf(a[rr].y, rv[1], acc[rr]);
            acc[rr] = fmaf(a[rr].z, rv[2], acc[rr]);
            acc[rr] = fmaf(a[rr].w, rv[3], acc[rr]);
        }
    }
    int p = b*8 + chunk;
    #pragma unroll
    for (int rr = 0; rr < 6; ++rr) {
        int i = i0 + rr;
        x[((size_t)b*DD + i)*TT + t0 + lane] = acc[rr];
        float ls = acc[rr], ls2 = acc[rr]*acc[rr];
        #pragma unroll
        for (int o = 32; o > 0; o >>= 1) {
            ls  += __shfl_down(ls,  o, 64);
            ls2 += __shfl_down(ls2, o, 64);
        }
        if (lane == 0) { P1[i*128 + p] = ls; P2[i*128 + p] = ls2; }
    }
}

// K3: per 2 rows: reduce the 128 partials of each row's channel -> sc/sh, then
// normalize + cast, writing xrow (row-major) and xfrag (gemm1-A-frag).
__global__ __launch_bounds__(256) void k_bnx(const float* __restrict__ x,
                                             const float* __restrict__ P1,
                                             const float* __restrict__ P2,
                                             const float* __restrict__ g,
                                             const float* __restrict__ bt,
                                             uint16_t* __restrict__ xrow,
                                             uint16_t* __restrict__ xfrag) {
    __shared__ float rr1[4], rr2[4], scsh[4];
    int blk = blockIdx.x;
    int tid = threadIdx.x;
    int wid = tid >> 6, lane = tid & 63;
    int r0 = blk*2;
    int d0 = r0 % DD, d1 = (r0+1) % DD;
    int d = (wid < 2) ? d0 : d1;
    int p = (wid & 1)*64 + lane;
    float v1 = P1[d*128 + p], v2 = P2[d*128 + p];
    #pragma unroll
    for (int o = 32; o > 0; o >>= 1) {
        v1 += __shfl_down(v1, o, 64);
        v2 += __shfl_down(v2, o, 64);
    }
    if (lane == 0) { rr1[wid] = v1; rr2[wid] = v2; }
    __syncthreads();
    if (tid < 2) {
        float s1 = rr1[tid*2] + rr1[tid*2+1];
        float s2 = rr2[tid*2] + rr2[tid*2+1];
        const float invn = 1.0f / (float)(BB*TT);
        float mu  = s1 * invn;
        float var = s2 * invn - mu*mu;
        float rs  = rsqrtf(var + 1e-5f);
        int dd = (tid == 0) ? d0 : d1;
        float scale = rs * g[dd];
        scsh[tid*2]   = scale;
        scsh[tid*2+1] = bt[dd] - mu*scale;
    }
    __syncthreads();
    int half = tid >> 7;
    int row = r0 + half;
    int k0 = (tid & 127) * 4;
    float scd = scsh[half*2], shd = scsh[half*2+1];
    float4 v = *reinterpret_cast<const float4*>(&x[(size_t)row*TT + k0]);
    ushort4 o;
    o.x = f2bf(v.x*scd + shd);
    o.y = f2bf(v.y*scd + shd);
    o.z = f2bf(v.z*scd + shd);
    o.w = f2bf(v.w*scd + shd);
    *reinterpret_cast<ushort4*>(&xrow[(size_t)row*TT + k0]) = o;
    size_t slot = afrag1_slot(row, k0);
    *reinterpret_cast<ushort4*>(&xfrag[slot*8 + (k0 & 7)]) = o;
}

// K4: fused MLP: h = gelu(xn@W1+b1) [LDS]; y = h@W2+b2+xn; out = LN(y).
// grid 96 x 512 (8 waves). Block = 16 rows. Wave w: phase1 cols w*128..+127,
// phase2 cols w*64..+63. h kept in LDS in gemm2-A-frag layout.
__global__ __launch_bounds__(512) void k_mlp(const uint16_t* __restrict__ xfrag,
                                             const uint16_t* __restrict__ w1bf,
                                             const uint16_t* __restrict__ w2bf,
                                             const float* __restrict__ b1,
                                             const float* __restrict__ b2,
                                             const uint16_t* __restrict__ xrow,
                                             const float* __restrict__ lng,
                                             const float* __restrict__ lnb,
                                             float* __restrict__ out) {
    __shared__ __align__(16) uint16_t hls[32*512];   // 32 KB: [ktile2][lane][8]
    __shared__ float lnp1[16][8], lnp2[16][8];
    __shared__ float lnmu[16], lnrs[16];
    int tid = threadIdx.x;
    int w = tid >> 6, lane = tid & 63;
    int q = lane >> 4, l15 = lane & 15;
    int mtile = blockIdx.x, m0 = mtile*16;

    // ---- phase 1: h = gelu(xn @ W1 + b1) ----
    short8 a1[16];
    {
        const uint16_t* ap = xfrag + ((size_t)mtile*KT1*64 + lane)*8;
        #pragma unroll
        for (int kk = 0; kk < KT1; ++kk)
            a1[kk] = *reinterpret_cast<const short8*>(ap + kk*512);
    }
    #pragma unroll
    for (int nf = 0; nf < 8; ++nf) {
        floatx4 acc = {};
        const uint16_t* bp = w1bf + (((size_t)(w*8 + nf))*16*64 + lane)*8;
        #pragma unroll
        for (int kk = 0; kk < 16; ++kk) {
            short8 b = *reinterpret_cast<const short8*>(bp + kk*512);
            acc = __builtin_amdgcn_mfma_f32_16x16x32_bf16(a1[kk], b, acc, 0, 0, 0);
        }
        int hcol = w*128 + nf*16 + l15;
        float bias = b1[hcol];
        int base = (hcol >> 5)*512 + (((hcol >> 3) & 3)*16)*8 + (hcol & 7);
        #pragma unroll
        for (int r = 0; r < 4; ++r) {
            float v = acc[r] + bias;
            float gl = 0.5f * v * (1.0f + erff(v * 0.7071067811865475f));
            int row = q*4 + r;
            hls[base + row*8] = f2bf(gl);
        }
    }
    __syncthreads();

    // ---- phase 2: y = h @ W2 + b2 + xn ----
    floatx4 acc2[4] = {};
    for (int half = 0; half < 2; ++half) {
        short8 a2[16];
        #pragma unroll
        for (int kk = 0; kk < 16; ++kk)
            a2[kk] = *reinterpret_cast<const short8*>(&hls[(half*16 + kk)*512 + lane*8]);
        #pragma unroll
        for (int nf2 = 0; nf2 < 4; ++nf2) {
            const uint16_t* bp = w2bf + (((size_t)(w*4 + nf2)*32 + half*16)*64 + lane)*8;
            #pragma unroll
            for (int kk = 0; kk < 16; ++kk) {
                short8 b = *reinterpret_cast<const short8*>(bp + kk*512);
                acc2[nf2] = __builtin_amdgcn_mfma_f32_16x16x32_bf16(a2[kk], b, acc2[nf2], 0, 0, 0);
            }
        }
    }
    float ya[4][4];
    float p1[4] = {0,0,0,0}, p2[4] = {0,0,0,0};
    #pragma unroll
    for (int nf2 = 0; nf2 < 4; ++nf2) {
        int col = w*64 + nf2*16 + l15;
        float bias = b2[col];
        #pragma unroll
        for (int r = 0; r < 4; ++r) {
            int row = q*4 + r;
            float v = acc2[nf2][r] + bias + bf2f(xrow[(size_t)(m0+row)*TT + col]);
            ya[nf2][r] = v;
            p1[r] += v;
            p2[r] += v*v;
        }
    }
    // ---- phase 3: LayerNorm over the full 512 cols ----
    #pragma unroll
    for (int r = 0; r < 4; ++r) {
        #pragma unroll
        for (int o = 1; o < 16; o <<= 1) {
            p1[r] += __shfl_xor(p1[r], o, 64);
            p2[r] += __shfl_xor(p2[r], o, 64);
        }
    }
    if (l15 == 0) {
        #pragma unroll
        for (int r = 0; r < 4; ++r) {
            lnp1[q*4 + r][w] = p1[r];
            lnp2[q*4 + r][w] = p2[r];
        }
    }
    __syncthreads();
    if (tid < 16) {
        float s1 = 0.f, s2 = 0.f;
        #pragma unroll
        for (int ww = 0; ww < 8; ++ww) { s1 += lnp1[tid][ww]; s2 += lnp2[tid][ww]; }
        float mu = s1 * (1.0f/TT);
        float var = s2 * (1.0f/TT) - mu*mu;
        lnmu[tid] = mu;
        lnrs[tid] = rsqrtf(var + 1e-5f);
    }
    __syncthreads();
    #pragma unroll
    for (int nf2 = 0; nf2 < 4; ++nf2) {
        int col = w*64 + nf2*16 + l15;
        float gg = lng[col], bb = lnb[col];
        #pragma unroll
        for (int r = 0; r < 4; ++r) {
            int row = q*4 + r;
            out[(size_t)(m0+row)*TT + col] = (ya[nf2][r] - lnmu[row]) * lnrs[row] * gg + bb;
        }
    }
}

extern "C" void kernel_launch(void* const* d_in, const int* in_sizes, int n_in,
                              void* d_out, int out_size, void* d_ws, size_t ws_size,
                              hipStream_t stream) {
    (void)in_sizes; (void)n_in; (void)out_size; (void)ws_size;
    const float* residual = (const float*)d_in[0];
    const float* bng = (const float*)d_in[1];
    const float* bnb = (const float*)d_in[2];
    const float* lng = (const float*)d_in[3];
    const float* lnb = (const float*)d_in[4];
    const float* W1  = (const float*)d_in[5];
    const float* b1  = (const float*)d_in[6];
    const float* W2  = (const float*)d_in[7];
    const float* b2  = (const float*)d_in[8];
    float* out = (float*)d_out;
    char* ws = (char*)d_ws;
    float*    x     = (float*)(ws + WSOFF_X);
    uint16_t* xrow  = (uint16_t*)(ws + WSOFF_XROW);
    uint16_t* xfrag = (uint16_t*)(ws + WSOFF_XFRAG);
    uint16_t* w1bf  = (uint16_t*)(ws + WSOFF_W1BF);
    uint16_t* w2bf  = (uint16_t*)(ws + WSOFF_W2BF);
    float*    A     = (float*)(ws + WSOFF_A);
    float*    P1    = (float*)(ws + WSOFF_P1);
    float*    P2    = (float*)(ws + WSOFF_P2);

    k_prep<<<BB, 256, 0, stream>>>(residual, A);
    k_attw<<<1024, 256, 0, stream>>>(residual, A, W1, W2, x, w1bf, w2bf, P1, P2);
    k_bnx<<<NROW/2, 256, 0, stream>>>(x, P1, P2, bng, bnb, xrow, xfrag);
    k_mlp<<<DD, 512, 0, stream>>>(xfrag, w1bf, w2bf, b1, b2, xrow, lng, lnb, out);
}

// Round 8
// 127.918 us; speedup vs baseline: 1.2313x; 1.2313x over previous
//
#include <hip/hip_runtime.h>
#include <math.h>
#include <stdint.h>

#define BB 16
#define DD 96
#define TT 512
#define HH 1024
#define NROW (BB*DD)   // 1536

typedef __attribute__((ext_vector_type(4))) float floatx4;
typedef __attribute__((ext_vector_type(8))) short short8;

// ---------------- ws layout (bytes) ----------------
#define WSOFF_X     0                               // attn out fp32, 3MB; reused as hfrag bf16 3MB
#define WSOFF_HFRAG 0
#define WSOFF_XROW  (3*1024*1024)                   // xn row-major bf16, 1.5MB
#define WSOFF_XFRAG (WSOFF_XROW + NROW*TT*2)        // xn gemm1-A-frag bf16, 1.5MB
#define WSOFF_W1BF  (WSOFF_XFRAG + NROW*TT*2)       // 1MB
#define WSOFF_W2BF  (WSOFF_W1BF + TT*HH*2)          // 1MB
#define WSOFF_A     (WSOFF_W2BF + HH*TT*2)          // 576KB
#define WSOFF_P1    (WSOFF_A + BB*DD*DD*4)          // 96*128 fp32 partial sums
#define WSOFF_P2    (WSOFF_P1 + DD*128*4)           // 96*128 fp32 partial sumsq

__device__ __forceinline__ uint16_t f2bf(float v) {
    uint32_t u = __float_as_uint(v);
    uint32_t r = 0x7fffu + ((u >> 16) & 1u);
    return (uint16_t)((u + r) >> 16);
}
__device__ __forceinline__ float bf2f(uint16_t v) {
    return __uint_as_float(((uint32_t)v) << 16);
}

#define KT1 (TT/32)    // 16 k-tiles, gemm1 A
#define KT2 (HH/32)    // 32 k-tiles, gemm2 A
__device__ __forceinline__ size_t afrag1_slot(int row, int k) {
    return ((size_t)((row >> 4)*KT1 + (k >> 5))*64 + ((k >> 3) & 3)*16 + (row & 15));
}

// K1: per batch b: row sums (4 waves x 24 rows) then softmax -> A[b]
__global__ __launch_bounds__(256) void k_prep(const float* __restrict__ r,
                                              float* __restrict__ A) {
    __shared__ float sl[DD];
    int b = blockIdx.x;
    int tid = threadIdx.x;
    int w = tid >> 6, lane = tid & 63;
    for (int rr = 0; rr < 24; ++rr) {
        int i = w*24 + rr;
        const float* p = r + ((size_t)b*DD + i)*TT;
        float acc = 0.f;
        #pragma unroll
        for (int s = 0; s < TT/64; ++s) acc += p[lane + s*64];
        #pragma unroll
        for (int o = 32; o > 0; o >>= 1) acc += __shfl_down(acc, o, 64);
        if (lane == 0) sl[i] = acc;
    }
    __syncthreads();
    int i = tid;
    if (i < DD) {
        const float c = 1.0f / (512.0f * 22.627416997969522f);  // T^-1.5
        float si = sl[i] * c;
        float m = -1e30f;
        for (int j = 0; j < DD; ++j) m = fmaxf(m, si * sl[j]);
        float sum = 0.f;
        for (int j = 0; j < DD; ++j) sum += expf(si * sl[j] - m);
        float inv = 1.0f / sum;
        float* Ao = A + ((size_t)b*DD + i)*DD;
        for (int j = 0; j < DD; ++j) Ao[j] = expf(si * sl[j] - m) * inv;
    }
}

// K2: blocks [0,512): wswiz; [512,1024): attn + deterministic BN partials.
__global__ __launch_bounds__(256) void k_attw(const float* __restrict__ r,
                                              const float* __restrict__ A,
                                              const float* __restrict__ W1,
                                              const float* __restrict__ W2,
                                              float* __restrict__ x,
                                              uint16_t* __restrict__ w1bf,
                                              uint16_t* __restrict__ w2bf,
                                              float* __restrict__ P1,
                                              float* __restrict__ P2) {
    int bx = blockIdx.x;
    int tid = threadIdx.x;
    int w = tid >> 6, lane = tid & 63;
    if (bx < 512) {
        int blk = bx*4 + w;
        int q = lane >> 4, l15 = lane & 15;
        const float* W; uint16_t* out; int KT, N, b;
        if (blk < 1024) { W = W1; out = w1bf; KT = 16; N = 1024; b = blk; }
        else            { W = W2; out = w2bf; KT = 32; N = 512;  b = blk - 1024; }
        int tile_n = b / KT, tile_k = b % KT;
        const float* src = W + (size_t)(tile_k*32 + q*8)*N + tile_n*16 + l15;
        uint16_t tmp[8];
        #pragma unroll
        for (int j = 0; j < 8; ++j) tmp[j] = f2bf(src[(size_t)j*N]);
        uint16_t* dst = out + ((size_t)b*64 + lane)*8;
        *reinterpret_cast<ushort4*>(dst)     = *reinterpret_cast<ushort4*>(&tmp[0]);
        *reinterpret_cast<ushort4*>(dst + 4) = *reinterpret_cast<ushort4*>(&tmp[4]);
        return;
    }
    __shared__ float rlds[DD*64];
    int idx = bx - 512;
    int b = idx & 15, chunk = (idx >> 4) & 7, ig = idx >> 7;
    int t0 = chunk * 64;
    const float4* rb4 = reinterpret_cast<const float4*>(r + (size_t)b*DD*TT);
    float4* rl4 = reinterpret_cast<float4*>(rlds);
    #pragma unroll
    for (int s = 0; s < 6; ++s) {
        int ii = tid + s*256;
        rl4[ii] = rb4[(size_t)(ii >> 4)*(TT/4) + (t0 >> 2) + (ii & 15)];
    }
    __syncthreads();
    int wu = __builtin_amdgcn_readfirstlane(w);
    int i0 = ig*24 + wu*6;
    const float* Ab = A + ((size_t)b*DD + i0)*DD;
    float acc[6];
    #pragma unroll
    for (int rr = 0; rr < 6; ++rr) acc[rr] = rlds[(i0+rr)*64 + lane];
    #pragma unroll 4
    for (int j4 = 0; j4 < DD/4; ++j4) {
        float4 a[6];
        #pragma unroll
        for (int rr = 0; rr < 6; ++rr)
            a[rr] = *reinterpret_cast<const float4*>(Ab + rr*DD + j4*4);
        float rv[4];
        #pragma unroll
        for (int u = 0; u < 4; ++u) rv[u] = rlds[(j4*4+u)*64 + lane];
        #pragma unroll
        for (int rr = 0; rr < 6; ++rr) {
            acc[rr] = fmaf(a[rr].x, rv[0], acc[rr]);
            acc[rr] = fmaf(a[rr].y, rv[1], acc[rr]);
            acc[rr] = fmaf(a[rr].z, rv[2], acc[rr]);
            acc[rr] = fmaf(a[rr].w, rv[3], acc[rr]);
        }
    }
    int p = b*8 + chunk;
    #pragma unroll
    for (int rr = 0; rr < 6; ++rr) {
        int i = i0 + rr;
        x[((size_t)b*DD + i)*TT + t0 + lane] = acc[rr];
        float ls = acc[rr], ls2 = acc[rr]*acc[rr];
        #pragma unroll
        for (int o = 32; o > 0; o >>= 1) {
            ls  += __shfl_down(ls,  o, 64);
            ls2 += __shfl_down(ls2, o, 64);
        }
        if (lane == 0) { P1[i*128 + p] = ls; P2[i*128 + p] = ls2; }
    }
}

// K3: per 2 rows: reduce 128 partials -> BN affine; normalize + cast -> xrow, xfrag.
__global__ __launch_bounds__(256) void k_bnx(const float* __restrict__ x,
                                             const float* __restrict__ P1,
                                             const float* __restrict__ P2,
                                             const float* __restrict__ g,
                                             const float* __restrict__ bt,
                                             uint16_t* __restrict__ xrow,
                                             uint16_t* __restrict__ xfrag) {
    __shared__ float rr1[4], rr2[4], scsh[4];
    int blk = blockIdx.x;
    int tid = threadIdx.x;
    int wid = tid >> 6, lane = tid & 63;
    int r0 = blk*2;
    int d0 = r0 % DD, d1 = (r0+1) % DD;
    int d = (wid < 2) ? d0 : d1;
    int p = (wid & 1)*64 + lane;
    float v1 = P1[d*128 + p], v2 = P2[d*128 + p];
    #pragma unroll
    for (int o = 32; o > 0; o >>= 1) {
        v1 += __shfl_down(v1, o, 64);
        v2 += __shfl_down(v2, o, 64);
    }
    if (lane == 0) { rr1[wid] = v1; rr2[wid] = v2; }
    __syncthreads();
    if (tid < 2) {
        float s1 = rr1[tid*2] + rr1[tid*2+1];
        float s2 = rr2[tid*2] + rr2[tid*2+1];
        const float invn = 1.0f / (float)(BB*TT);
        float mu  = s1 * invn;
        float var = s2 * invn - mu*mu;
        float rs  = rsqrtf(var + 1e-5f);
        int dd = (tid == 0) ? d0 : d1;
        float scale = rs * g[dd];
        scsh[tid*2]   = scale;
        scsh[tid*2+1] = bt[dd] - mu*scale;
    }
    __syncthreads();
    int half = tid >> 7;
    int row = r0 + half;
    int k0 = (tid & 127) * 4;
    float scd = scsh[half*2], shd = scsh[half*2+1];
    float4 v = *reinterpret_cast<const float4*>(&x[(size_t)row*TT + k0]);
    ushort4 o;
    o.x = f2bf(v.x*scd + shd);
    o.y = f2bf(v.y*scd + shd);
    o.z = f2bf(v.z*scd + shd);
    o.w = f2bf(v.w*scd + shd);
    *reinterpret_cast<ushort4*>(&xrow[(size_t)row*TT + k0]) = o;
    size_t slot = afrag1_slot(row, k0);
    *reinterpret_cast<ushort4*>(&xfrag[slot*8 + (k0 & 7)]) = o;
}

// K4: h = gelu(xn @ W1 + b1) in gemm2-A-frag order. grid (96, 8) x 256. M=16, N=128.
// (R7 lesson: the fused 96-block k_mlp was latency-bound at 8% occupancy, 70us.
//  768 blocks -> 12 waves/CU, loads pipelined, was profiler-invisible in R6.)
__global__ __launch_bounds__(256) void k_gemm1(const uint16_t* __restrict__ xfrag,
                                               const uint16_t* __restrict__ w1bf,
                                               const float* __restrict__ b1,
                                               uint16_t* __restrict__ hfrag) {
    __shared__ __align__(16) uint16_t cs[16][136];
    int tid = threadIdx.x;
    int wave = tid >> 6, lane = tid & 63;
    int q = lane >> 4, l15 = lane & 15;
    int mtile = blockIdx.x;
    int n0 = blockIdx.y * 128 + wave * 32;
    floatx4 acc[2] = {};
    const uint16_t* ap  = xfrag + ((size_t)mtile*KT1*64 + lane)*8;
    const uint16_t* b0p = w1bf + ((size_t)((n0>>4)    )*16*64 + lane)*8;
    const uint16_t* b1p = w1bf + ((size_t)((n0>>4) + 1)*16*64 + lane)*8;
    #pragma unroll
    for (int kk = 0; kk < 16; ++kk) {
        short8 a  = *reinterpret_cast<const short8*>(ap  + kk*512);
        short8 b0 = *reinterpret_cast<const short8*>(b0p + kk*512);
        short8 b1 = *reinterpret_cast<const short8*>(b1p + kk*512);
        acc[0] = __builtin_amdgcn_mfma_f32_16x16x32_bf16(a, b0, acc[0], 0, 0, 0);
        acc[1] = __builtin_amdgcn_mfma_f32_16x16x32_bf16(a, b1, acc[1], 0, 0, 0);
    }
    #pragma unroll
    for (int nf = 0; nf < 2; ++nf) {
        int coll = wave*32 + nf*16 + l15;
        float bias = b1[blockIdx.y*128 + coll];
        #pragma unroll
        for (int r = 0; r < 4; ++r) {
            float v = acc[nf][r] + bias;
            float gl = 0.5f * v * (1.0f + erff(v * 0.7071067811865475f));
            cs[q*4 + r][coll] = f2bf(gl);
        }
    }
    __syncthreads();
    int c = wave;
    const uint4* src = reinterpret_cast<const uint4*>(&cs[l15][c*32 + q*8]);
    size_t chunk = (size_t)mtile*KT2 + (blockIdx.y*4 + c);
    reinterpret_cast<uint4*>(hfrag)[chunk*64 + lane] = *src;
}

// K5: y = h @ W2 + b2 + xn -> fp32. grid (96, 4) x 256. M=16, N=128.
__global__ __launch_bounds__(256) void k_gemm2(const uint16_t* __restrict__ hfrag,
                                               const uint16_t* __restrict__ w2bf,
                                               const float* __restrict__ b2,
                                               const uint16_t* __restrict__ xrow,
                                               float* __restrict__ y) {
    int tid = threadIdx.x;
    int wave = tid >> 6, lane = tid & 63;
    int q = lane >> 4, l15 = lane & 15;
    int mtile = blockIdx.x;
    int m0 = mtile * 16;
    int n0 = blockIdx.y * 128 + wave * 32;
    floatx4 acc[2] = {};
    const uint16_t* ap  = hfrag + ((size_t)mtile*KT2*64 + lane)*8;
    const uint16_t* b0p = w2bf + ((size_t)((n0>>4)    )*32*64 + lane)*8;
    const uint16_t* b1p = w2bf + ((size_t)((n0>>4) + 1)*32*64 + lane)*8;
    #pragma unroll
    for (int kk = 0; kk < 32; ++kk) {
        short8 a  = *reinterpret_cast<const short8*>(ap  + kk*512);
        short8 b0 = *reinterpret_cast<const short8*>(b0p + kk*512);
        short8 b1 = *reinterpret_cast<const short8*>(b1p + kk*512);
        acc[0] = __builtin_amdgcn_mfma_f32_16x16x32_bf16(a, b0, acc[0], 0, 0, 0);
        acc[1] = __builtin_amdgcn_mfma_f32_16x16x32_bf16(a, b1, acc[1], 0, 0, 0);
    }
    #pragma unroll
    for (int nf = 0; nf < 2; ++nf) {
        int col = n0 + nf*16 + l15;
        float bias = b2[col];
        #pragma unroll
        for (int r = 0; r < 4; ++r) {
            int row = m0 + q*4 + r;
            float xb = bf2f(xrow[(size_t)row*TT + col]);
            y[(size_t)row*TT + col] = acc[nf][r] + bias + xb;
        }
    }
}

// K6: LayerNorm per row over T=512, in-place on d_out. grid 1536 x 64.
__global__ __launch_bounds__(64) void k_ln(float* __restrict__ y,
                                           const float* __restrict__ lng,
                                           const float* __restrict__ lnb) {
    int row = blockIdx.x;
    int lane = threadIdx.x;
    float4* p = reinterpret_cast<float4*>(y + (size_t)row*TT);
    float4 v0 = p[lane*2], v1 = p[lane*2 + 1];
    float s  = v0.x+v0.y+v0.z+v0.w + v1.x+v1.y+v1.z+v1.w;
    float s2 = v0.x*v0.x+v0.y*v0.y+v0.z*v0.z+v0.w*v0.w
             + v1.x*v1.x+v1.y*v1.y+v1.z*v1.z+v1.w*v1.w;
    #pragma unroll
    for (int o = 1; o < 64; o <<= 1) {
        s  += __shfl_xor(s,  o, 64);
        s2 += __shfl_xor(s2, o, 64);
    }
    float mu = s * (1.0f/TT);
    float var = s2 * (1.0f/TT) - mu*mu;
    float rs = rsqrtf(var + 1e-5f);
    const float4* g4 = reinterpret_cast<const float4*>(lng);
    const float4* b4 = reinterpret_cast<const float4*>(lnb);
    float4 g0 = g4[lane*2], g1 = g4[lane*2+1];
    float4 bb0 = b4[lane*2], bb1 = b4[lane*2+1];
    float4 o0, o1;
    o0.x = (v0.x-mu)*rs*g0.x + bb0.x;  o0.y = (v0.y-mu)*rs*g0.y + bb0.y;
    o0.z = (v0.z-mu)*rs*g0.z + bb0.z;  o0.w = (v0.w-mu)*rs*g0.w + bb0.w;
    o1.x = (v1.x-mu)*rs*g1.x + bb1.x;  o1.y = (v1.y-mu)*rs*g1.y + bb1.y;
    o1.z = (v1.z-mu)*rs*g1.z + bb1.z;  o1.w = (v1.w-mu)*rs*g1.w + bb1.w;
    p[lane*2] = o0;  p[lane*2+1] = o1;
}

extern "C" void kernel_launch(void* const* d_in, const int* in_sizes, int n_in,
                              void* d_out, int out_size, void* d_ws, size_t ws_size,
                              hipStream_t stream) {
    (void)in_sizes; (void)n_in; (void)out_size; (void)ws_size;
    const float* residual = (const float*)d_in[0];
    const float* bng = (const float*)d_in[1];
    const float* bnb = (const float*)d_in[2];
    const float* lng = (const float*)d_in[3];
    const float* lnb = (const float*)d_in[4];
    const float* W1  = (const float*)d_in[5];
    const float* b1  = (const float*)d_in[6];
    const float* W2  = (const float*)d_in[7];
    const float* b2  = (const float*)d_in[8];
    float* out = (float*)d_out;
    char* ws = (char*)d_ws;
    float*    x     = (float*)(ws + WSOFF_X);
    uint16_t* hfrag = (uint16_t*)(ws + WSOFF_HFRAG);   // aliases x; x dead after k_bnx
    uint16_t* xrow  = (uint16_t*)(ws + WSOFF_XROW);
    uint16_t* xfrag = (uint16_t*)(ws + WSOFF_XFRAG);
    uint16_t* w1bf  = (uint16_t*)(ws + WSOFF_W1BF);
    uint16_t* w2bf  = (uint16_t*)(ws + WSOFF_W2BF);
    float*    A     = (float*)(ws + WSOFF_A);
    float*    P1    = (float*)(ws + WSOFF_P1);
    float*    P2    = (float*)(ws + WSOFF_P2);

    k_prep<<<BB, 256, 0, stream>>>(residual, A);
    k_attw<<<1024, 256, 0, stream>>>(residual, A, W1, W2, x, w1bf, w2bf, P1, P2);
    k_bnx<<<NROW/2, 256, 0, stream>>>(x, P1, P2, bng, bnb, xrow, xfrag);
    k_gemm1<<<dim3(96, 8), 256, 0, stream>>>(xfrag, w1bf, b1, hfrag);
    k_gemm2<<<dim3(96, 4), 256, 0, stream>>>(hfrag, w2bf, b2, xrow, out);
    k_ln<<<NROW, 64, 0, stream>>>(out, lng, lnb);
}